// Round 18
// baseline (36.174 us; speedup 1.0000x reference)
//
#include <hip/hip_runtime.h>

// NeRF backbone builder — R15 half-LDS structure + 2-chunks-per-lane ILP.
// Lane k builds chunk k (steps 4k..4k+3, "A") AND chunk 64+k (steps
// 256+4k.., "B") — two independent 4-step chains interleave -> 2x ILP on
// the serial step3 dependency chain (the R15..R17 residual). Two in-wave
// scans (A,B, interleaved) + T1-compose (= R8's proven handoff, in-wave).
// Shifted-window staging: half0 rows 4k..4k+3 from A, half1 from B.

struct V3 { float x, y, z; };

__device__ __forceinline__ V3 vsub(V3 a, V3 b){ return {a.x-b.x, a.y-b.y, a.z-b.z}; }
__device__ __forceinline__ V3 vcross(V3 a, V3 b){
    return {a.y*b.z - a.z*b.y, a.z*b.x - a.x*b.z, a.x*b.y - a.y*b.x};
}
__device__ __forceinline__ float vdot(V3 a, V3 b){ return a.x*b.x + a.y*b.y + a.z*b.z; }
__device__ __forceinline__ V3 vunit(V3 a){
    float r = rsqrtf(vdot(a,a));
    return {a.x*r, a.y*r, a.z*r};
}

struct Xform { V3 c0, c1, c2, t; };  // p' = c0*px + c1*py + c2*pz + t

__device__ __forceinline__ V3 xrot(const Xform& X, V3 p){
    return { X.c0.x*p.x + X.c1.x*p.y + X.c2.x*p.z,
             X.c0.y*p.x + X.c1.y*p.y + X.c2.y*p.z,
             X.c0.z*p.x + X.c1.z*p.y + X.c2.z*p.z };
}
__device__ __forceinline__ V3 xapply(const Xform& X, V3 p){
    V3 r = xrot(X, p);
    return { r.x + X.t.x, r.y + X.t.y, r.z + X.t.z };
}
__device__ __forceinline__ Xform xcompose(const Xform& A, const Xform& B){ // A∘B (B first)
    Xform R;
    R.c0 = xrot(A, B.c0);
    R.c1 = xrot(A, B.c1);
    R.c2 = xrot(A, B.c2);
    R.t  = xapply(A, B.t);
    return R;
}

__device__ __forceinline__ Xform frame_of(V3 A, V3 B, V3 C){
    V3 bc  = vunit(vsub(C, B));
    V3 n   = vunit(vcross(vsub(B, A), bc));
    V3 nbc = vcross(n, bc);
    return { bc, nbc, n, C };
}

__device__ __forceinline__ Xform shfl_up_xf(const Xform& X, int d){
    Xform R;
    R.c0.x = __shfl_up(X.c0.x, d); R.c0.y = __shfl_up(X.c0.y, d); R.c0.z = __shfl_up(X.c0.z, d);
    R.c1.x = __shfl_up(X.c1.x, d); R.c1.y = __shfl_up(X.c1.y, d); R.c1.z = __shfl_up(X.c1.z, d);
    R.c2.x = __shfl_up(X.c2.x, d); R.c2.y = __shfl_up(X.c2.y, d); R.c2.z = __shfl_up(X.c2.z, d);
    R.t.x  = __shfl_up(X.t.x,  d); R.t.y  = __shfl_up(X.t.y,  d); R.t.z  = __shfl_up(X.t.z,  d);
    return R;
}
__device__ __forceinline__ Xform shfl_bc_xf(const Xform& X, int lane){
    Xform R;
    R.c0.x = __shfl(X.c0.x, lane); R.c0.y = __shfl(X.c0.y, lane); R.c0.z = __shfl(X.c0.z, lane);
    R.c1.x = __shfl(X.c1.x, lane); R.c1.y = __shfl(X.c1.y, lane); R.c1.z = __shfl(X.c1.z, lane);
    R.c2.x = __shfl(X.c2.x, lane); R.c2.y = __shfl(X.c2.y, lane); R.c2.z = __shfl(X.c2.z, lane);
    R.t.x  = __shfl(X.t.x,  lane); R.t.y  = __shfl(X.t.y,  lane); R.t.z  = __shfl(X.t.z,  lane);
    return R;
}

// Bond constants: d0 = -L*cos(theta), Ls = L*sin(theta)
#define D0_CN   0.56630847f
#define LS_CN   1.21445243f
#define D0_NCA  0.75195559f
#define LS_NCA  1.25146426f
#define D0_CAC  0.50137496f
#define LS_CAC  1.45609861f

// Canonical incoming triple in its own frame (HW-validated R2..R17)
#define A0X (-2.0153295f)
#define A0Y ( 1.3804571f)

// World init triple
#define NIX 17.047f
#define NIY 14.099f
#define NIZ  3.625f
#define CAX 16.967f
#define CAY 12.784f
#define CAZ  4.338f
#define CIX 15.685f
#define CIY 12.755f
#define CIZ  5.133f

__device__ __forceinline__ V3 place_dihedral(V3 a, V3 b, V3 c,
                                             float d0, float Ls, float tor){
    V3 ab = vsub(b, a);
    V3 bc = vunit(vsub(c, b));
    V3 n  = vunit(vcross(ab, bc));
    V3 nbc = vcross(n, bc);
    float sn, cs;
    __sincosf(tor, &sn, &cs);
    float d1 = Ls * cs;
    float d2 = Ls * sn;
    return { c.x + d0*bc.x + d1*nbc.x + d2*n.x,
             c.y + d0*bc.y + d1*nbc.y + d2*n.y,
             c.z + d0*bc.z + d1*nbc.z + d2*n.z };
}

__device__ __forceinline__ void step3(V3& A, V3& B, V3& C,
                                      float tpsi, float tome, float tphi){
    V3 dn  = place_dihedral(A, B, C,  D0_CN,  LS_CN,  tpsi);
    V3 dca = place_dihedral(B, C, dn, D0_NCA, LS_NCA, tome);
    V3 dc  = place_dihedral(C, dn, dca, D0_CAC, LS_CAC, tphi);
    A = dn; B = dca; C = dc;
}

// float4-granular XOR swizzle (involution) — proven R10/R12/R14/R15 pair.
__device__ __forceinline__ void put4(float4* lds4, int p, float4 v){
    lds4[p ^ ((p >> 6) & 7)] = v;
}

// Stage 4 rows (36 floats = 9 float4) starting at float4 index p.
__device__ __forceinline__ void stage36(float4* lds4, int p,
    V3 aA, V3 aB, V3 aC, V3 bA, V3 bB, V3 bC,
    V3 cA, V3 cB, V3 cC, V3 dA, V3 dB, V3 dC){
    put4(lds4, p+0, make_float4(aA.x, aA.y, aA.z, aB.x));
    put4(lds4, p+1, make_float4(aB.y, aB.z, aC.x, aC.y));
    put4(lds4, p+2, make_float4(aC.z, bA.x, bA.y, bA.z));
    put4(lds4, p+3, make_float4(bB.x, bB.y, bB.z, bC.x));
    put4(lds4, p+4, make_float4(bC.y, bC.z, cA.x, cA.y));
    put4(lds4, p+5, make_float4(cA.z, cB.x, cB.y, cB.z));
    put4(lds4, p+6, make_float4(cC.x, cC.y, cC.z, dA.x));
    put4(lds4, p+7, make_float4(dA.y, dA.z, dB.x, dB.y));
    put4(lds4, p+8, make_float4(dB.z, dC.x, dC.y, dC.z));
}

// ---- Fused kernel: one wave per chain, 2 chunks per lane ----
__global__ __launch_bounds__(64, 3)
void nerf_dual(const float* __restrict__ phi,
               const float* __restrict__ psi,
               const float* __restrict__ omega,
               float* __restrict__ out,
               int steps){
    const int L = 512;
    int b = blockIdx.x;
    int k = threadIdx.x;
    int sA = 4 * k;                   // A-chunk first step (rows 4k+1..)
    int sB = 256 + 4 * k;             // B-chunk first step

    __shared__ float4 lds4[576];      // 9216 B = half chain

    const float* pphi = phi   + (size_t)b * L;
    const float* ppsi = psi   + (size_t)b * L;
    const float* pome = omega + (size_t)b * L;

    float4 psA = *(const float4*)(ppsi + sA);
    float4 psB = *(const float4*)(ppsi + sB);
    float4 omA = *(const float4*)(pome + sA);
    float4 omB = *(const float4*)(pome + sB);
    float4 phA = *(const float4*)(pphi + sA);
    float4 phB = *(const float4*)(pphi + sB);
    float phnA  = __shfl_down(phA.x, 1);    // phi[sA+4]
    float ph256 = __shfl(phB.x, 0);         // phi[256] (lane0's B load)
    if (k == 63) phnA = ph256;              // lane63-A step 255 needs phi[256]
    float phnB  = __shfl_down(phB.x, 1);    // phi[sB+4]; lane63 use is masked

    float tpsiA[4] = {psA.x, psA.y, psA.z, psA.w};
    float tomeA[4] = {omA.x, omA.y, omA.z, omA.w};
    float tphiA[4] = {phA.y, phA.z, phA.w, phnA};
    float tpsiB[4] = {psB.x, psB.y, psB.z, psB.w};
    float tomeB[4] = {omB.x, omB.y, omB.z, omB.w};
    float tphiB[4] = {phB.y, phB.z, phB.w, phnB};

    // ---- pass 1: two INDEPENDENT chunk builds (2x ILP on the step chain) ----
    V3 Aa, Ba, Ca, Ab, Bb, Cb;
    if (k == 0){
        Aa = {NIX, NIY, NIZ}; Ba = {CAX, CAY, CAZ}; Ca = {CIX, CIY, CIZ};
    } else {
        Aa = {A0X, A0Y, 0.f}; Ba = {-1.54f, 0.f, 0.f}; Ca = {0.f, 0.f, 0.f};
    }
    Ab = {A0X, A0Y, 0.f}; Bb = {-1.54f, 0.f, 0.f}; Cb = {0.f, 0.f, 0.f};

    V3 lAa[4], lBa[4], lCa[4], lAb[4], lBb[4], lCb[4];
    #pragma unroll
    for (int s = 0; s < 4; ++s){
        step3(Aa, Ba, Ca, tpsiA[s], tomeA[s], tphiA[s]);           // always active
        if (sB + s < steps)
            step3(Ab, Bb, Cb, tpsiB[s], tomeB[s], tphiB[s]);       // lane63 s=3 masked
        lAa[s] = Aa; lBa[s] = Ba; lCa[s] = Ca;
        lAb[s] = Ab; lBb[s] = Bb; lCb[s] = Cb;
    }
    Xform Va = frame_of(Aa, Ba, Ca);
    Xform Vb = frame_of(Ab, Bb, Cb);

    // ---- two interleaved in-wave scans (independent -> co-issue) ----
    #pragma unroll
    for (int d = 1; d < 64; d <<= 1){
        Xform Pa = shfl_up_xf(Va, d);
        Xform Pb = shfl_up_xf(Vb, d);
        if (k >= d){ Va = xcompose(Pa, Va); Vb = xcompose(Pb, Vb); }
    }
    Xform T1  = shfl_bc_xf(Va, 63);   // world transform through step 255
    Xform Wpa = shfl_up_xf(Va, 1);    // A-prefix through lane k-1 (lane0 unused)
    Xform Upb = shfl_up_xf(Vb, 1);    // B-local prefix through lane k-1

    // ---- pass 3: transform locals to world IN PLACE ----
    if (k != 0){
        #pragma unroll
        for (int s = 0; s < 4; ++s){
            lAa[s] = xapply(Wpa, lAa[s]);
            lBa[s] = xapply(Wpa, lBa[s]);
            lCa[s] = xapply(Wpa, lCa[s]);
        }
    }
    Xform Wpb = (k == 0) ? T1 : xcompose(T1, Upb);  // = R8's proven handoff math
    #pragma unroll
    for (int s = 0; s < 4; ++s){
        lAb[s] = xapply(Wpb, lAb[s]);
        lBb[s] = xapply(Wpb, lBb[s]);
        lCb[s] = xapply(Wpb, lCb[s]);
    }

    // ---- neighbor rows (shifted window) ----
    // half0 row 4k = lane k-1's A s=3 (lane0: init triple)
    V3 nAa, nBa, nCa;
    nAa.x = __shfl_up(lAa[3].x, 1); nAa.y = __shfl_up(lAa[3].y, 1); nAa.z = __shfl_up(lAa[3].z, 1);
    nBa.x = __shfl_up(lBa[3].x, 1); nBa.y = __shfl_up(lBa[3].y, 1); nBa.z = __shfl_up(lBa[3].z, 1);
    nCa.x = __shfl_up(lCa[3].x, 1); nCa.y = __shfl_up(lCa[3].y, 1); nCa.z = __shfl_up(lCa[3].z, 1);
    // half1 row 256+4k = lane k-1's B s=3 (lane0: lane63's A s=3 = row 256)
    float bAx = __shfl(lAa[3].x, 63), bAy = __shfl(lAa[3].y, 63), bAz = __shfl(lAa[3].z, 63);
    float bBx = __shfl(lBa[3].x, 63), bBy = __shfl(lBa[3].y, 63), bBz = __shfl(lBa[3].z, 63);
    float bCx = __shfl(lCa[3].x, 63), bCy = __shfl(lCa[3].y, 63), bCz = __shfl(lCa[3].z, 63);
    V3 nAb, nBb, nCb;
    nAb.x = __shfl_up(lAb[3].x, 1); nAb.y = __shfl_up(lAb[3].y, 1); nAb.z = __shfl_up(lAb[3].z, 1);
    nBb.x = __shfl_up(lBb[3].x, 1); nBb.y = __shfl_up(lBb[3].y, 1); nBb.z = __shfl_up(lBb[3].z, 1);
    nCb.x = __shfl_up(lCb[3].x, 1); nCb.y = __shfl_up(lCb[3].y, 1); nCb.z = __shfl_up(lCb[3].z, 1);
    if (k == 0){
        nAa = {NIX, NIY, NIZ}; nBa = {CAX, CAY, CAZ}; nCa = {CIX, CIY, CIZ};
        nAb = {bAx, bAy, bAz}; nBb = {bBx, bBy, bBz}; nCb = {bCx, bCy, bCz};
    }

    int p0 = 9 * k;
    float4* o4 = (float4*)(out + (size_t)b * 4608u);

    // ---- half 0: rows 4k..4k+3 (neighbor + A s=0..2); A s=3 went via shfl ----
    stage36(lds4, p0, nAa, nBa, nCa, lAa[0], lBa[0], lCa[0],
                      lAa[1], lBa[1], lCa[1], lAa[2], lBa[2], lCa[2]);
    __syncthreads();
    #pragma unroll
    for (int i = 0; i < 9; ++i){
        int q = i * 64 + k;
        o4[q] = lds4[q ^ ((q >> 6) & 7)];
    }
    __syncthreads();

    // ---- half 1: rows 256+4k..259+4k (neighbor + B s=0..2) ----
    stage36(lds4, p0, nAb, nBb, nCb, lAb[0], lBb[0], lCb[0],
                      lAb[1], lBb[1], lCb[1], lAb[2], lBb[2], lCb[2]);
    __syncthreads();
    #pragma unroll
    for (int i = 0; i < 9; ++i){
        int q = i * 64 + k;
        o4[576 + q] = lds4[q ^ ((q >> 6) & 7)];
    }
}

// ---- Fallback: sequential one-thread-per-chain (general sizes) ----
__global__ void nerf_seq_kernel(const float* __restrict__ phi,
                                const float* __restrict__ psi,
                                const float* __restrict__ omega,
                                float* __restrict__ out,
                                int B, int L, int steps){
    int b = blockIdx.x * blockDim.x + threadIdx.x;
    if (b >= B) return;
    V3 A  = {NIX, NIY, NIZ};
    V3 Bv = {CAX, CAY, CAZ};
    V3 C  = {CIX, CIY, CIZ};
    float* o = out + (size_t)b * 9u * (size_t)(steps + 1);
    o[0]=A.x;  o[1]=A.y;  o[2]=A.z;
    o[3]=Bv.x; o[4]=Bv.y; o[5]=Bv.z;
    o[6]=C.x;  o[7]=C.y;  o[8]=C.z;
    const float* pphi = phi   + (size_t)b * L;
    const float* ppsi = psi   + (size_t)b * L;
    const float* pome = omega + (size_t)b * L;
    for (int s = 0; s < steps; ++s){
        step3(A, Bv, C, ppsi[s], pome[s], pphi[s + 1]);
        float* os = o + 9u * (size_t)(s + 1);
        os[0]=A.x;  os[1]=A.y;  os[2]=A.z;
        os[3]=Bv.x; os[4]=Bv.y; os[5]=Bv.z;
        os[6]=C.x;  os[7]=C.y;  os[8]=C.z;
    }
}

extern "C" void kernel_launch(void* const* d_in, const int* in_sizes, int n_in,
                              void* d_out, int out_size, void* d_ws, size_t ws_size,
                              hipStream_t stream) {
    const float* phi   = (const float*)d_in[0];
    const float* psi   = (const float*)d_in[1];
    const float* omega = (const float*)d_in[2];
    float* out = (float*)d_out;

    const int L = 512;
    int B = in_sizes[0] / L;
    int steps = out_size / (9 * B) - 1;

    if (steps == 511 && in_sizes[0] == B * 512) {
        nerf_dual<<<B, 64, 0, stream>>>(phi, psi, omega, out, steps);
    } else {
        int block = 64;
        int grid = (B + block - 1) / block;
        nerf_seq_kernel<<<grid, block, 0, stream>>>(phi, psi, omega, out, B, L, steps);
    }
}

// Round 20
// 30.821 us; speedup vs baseline: 1.1737x; 1.1737x over previous
//
#include <hip/hip_runtime.h>

// NeRF backbone builder — FINAL: R15 verbatim (best fully-validated kernel,
// 30.8µs, 10.2x over baseline). Structure: 1 wave/chain, S=8 chunk/lane ->
// local build (renormalizing step3) -> 6-level in-wave rigid-transform scan
// -> in-place world transform -> half-LDS (9216B) shifted-window vectorized
// staging (put4 XOR swizzle) -> coalesced float4 flush.
// Convicted-and-reverted levers (fail validation, mechanism unidentified):
//   - constant-scale rigid-geometry step math (R4/R5/R7: inf/NaN)
//   - packed-FP32 f2 layout (R19: post-timing divergence)
// Null levers (proven not binding): occupancy caps (R16/R17), rsqrt dep
// reorder (R16), 2-chunk ILP (R18: issue-bound, +instrs = +time).

struct V3 { float x, y, z; };

__device__ __forceinline__ V3 vsub(V3 a, V3 b){ return {a.x-b.x, a.y-b.y, a.z-b.z}; }
__device__ __forceinline__ V3 vcross(V3 a, V3 b){
    return {a.y*b.z - a.z*b.y, a.z*b.x - a.x*b.z, a.x*b.y - a.y*b.x};
}
__device__ __forceinline__ float vdot(V3 a, V3 b){ return a.x*b.x + a.y*b.y + a.z*b.z; }
__device__ __forceinline__ V3 vunit(V3 a){
    float r = rsqrtf(vdot(a,a));
    return {a.x*r, a.y*r, a.z*r};
}

struct Xform { V3 c0, c1, c2, t; };  // p' = c0*px + c1*py + c2*pz + t

__device__ __forceinline__ V3 xrot(const Xform& X, V3 p){
    return { X.c0.x*p.x + X.c1.x*p.y + X.c2.x*p.z,
             X.c0.y*p.x + X.c1.y*p.y + X.c2.y*p.z,
             X.c0.z*p.x + X.c1.z*p.y + X.c2.z*p.z };
}
__device__ __forceinline__ V3 xapply(const Xform& X, V3 p){
    V3 r = xrot(X, p);
    return { r.x + X.t.x, r.y + X.t.y, r.z + X.t.z };
}
__device__ __forceinline__ Xform xcompose(const Xform& A, const Xform& B){ // A∘B (B first)
    Xform R;
    R.c0 = xrot(A, B.c0);
    R.c1 = xrot(A, B.c1);
    R.c2 = xrot(A, B.c2);
    R.t  = xapply(A, B.t);
    return R;
}

__device__ __forceinline__ Xform frame_of(V3 A, V3 B, V3 C){
    V3 bc  = vunit(vsub(C, B));
    V3 n   = vunit(vcross(vsub(B, A), bc));
    V3 nbc = vcross(n, bc);
    return { bc, nbc, n, C };
}

__device__ __forceinline__ Xform shfl_up_xf(const Xform& X, int d){
    Xform R;
    R.c0.x = __shfl_up(X.c0.x, d); R.c0.y = __shfl_up(X.c0.y, d); R.c0.z = __shfl_up(X.c0.z, d);
    R.c1.x = __shfl_up(X.c1.x, d); R.c1.y = __shfl_up(X.c1.y, d); R.c1.z = __shfl_up(X.c1.z, d);
    R.c2.x = __shfl_up(X.c2.x, d); R.c2.y = __shfl_up(X.c2.y, d); R.c2.z = __shfl_up(X.c2.z, d);
    R.t.x  = __shfl_up(X.t.x,  d); R.t.y  = __shfl_up(X.t.y,  d); R.t.z  = __shfl_up(X.t.z,  d);
    return R;
}

// Bond constants: d0 = -L*cos(theta), Ls = L*sin(theta)
#define D0_CN   0.56630847f
#define LS_CN   1.21445243f
#define D0_NCA  0.75195559f
#define LS_NCA  1.25146426f
#define D0_CAC  0.50137496f
#define LS_CAC  1.45609861f

// Canonical incoming triple in its own frame (HW-validated R2..R18)
#define A0X (-2.0153295f)
#define A0Y ( 1.3804571f)

// World init triple
#define NIX 17.047f
#define NIY 14.099f
#define NIZ  3.625f
#define CAX 16.967f
#define CAY 12.784f
#define CAZ  4.338f
#define CIX 15.685f
#define CIY 12.755f
#define CIZ  5.133f

__device__ __forceinline__ V3 place_dihedral(V3 a, V3 b, V3 c,
                                             float d0, float Ls, float tor){
    V3 ab = vsub(b, a);
    V3 bc = vunit(vsub(c, b));
    V3 n  = vunit(vcross(ab, bc));
    V3 nbc = vcross(n, bc);
    float sn, cs;
    __sincosf(tor, &sn, &cs);
    float d1 = Ls * cs;
    float d2 = Ls * sn;
    return { c.x + d0*bc.x + d1*nbc.x + d2*n.x,
             c.y + d0*bc.y + d1*nbc.y + d2*n.y,
             c.z + d0*bc.z + d1*nbc.z + d2*n.z };
}

__device__ __forceinline__ void step3(V3& A, V3& B, V3& C,
                                      float tpsi, float tome, float tphi){
    V3 dn  = place_dihedral(A, B, C,  D0_CN,  LS_CN,  tpsi);
    V3 dca = place_dihedral(B, C, dn, D0_NCA, LS_NCA, tome);
    V3 dc  = place_dihedral(C, dn, dca, D0_CAC, LS_CAC, tphi);
    A = dn; B = dca; C = dc;
}

// float4-granular XOR swizzle (involution) — proven R10/R12/R14/R15 pair.
__device__ __forceinline__ void put4(float4* lds4, int p, float4 v){
    lds4[p ^ ((p >> 6) & 7)] = v;
}

// Stage 4 rows (36 floats = 9 float4) starting at float4 index p.
__device__ __forceinline__ void stage36(float4* lds4, int p,
    V3 aA, V3 aB, V3 aC, V3 bA, V3 bB, V3 bC,
    V3 cA, V3 cB, V3 cC, V3 dA, V3 dB, V3 dC){
    put4(lds4, p+0, make_float4(aA.x, aA.y, aA.z, aB.x));
    put4(lds4, p+1, make_float4(aB.y, aB.z, aC.x, aC.y));
    put4(lds4, p+2, make_float4(aC.z, bA.x, bA.y, bA.z));
    put4(lds4, p+3, make_float4(bB.x, bB.y, bB.z, bC.x));
    put4(lds4, p+4, make_float4(bC.y, bC.z, cA.x, cA.y));
    put4(lds4, p+5, make_float4(cA.z, cB.x, cB.y, cB.z));
    put4(lds4, p+6, make_float4(cC.x, cC.y, cC.z, dA.x));
    put4(lds4, p+7, make_float4(dA.y, dA.z, dB.x, dB.y));
    put4(lds4, p+8, make_float4(dB.z, dC.x, dC.y, dC.z));
}

// ---- Fused kernel: one wave per chain, half-LDS staging ----
__global__ __launch_bounds__(64)
void nerf_half(const float* __restrict__ phi,
               const float* __restrict__ psi,
               const float* __restrict__ omega,
               float* __restrict__ out,
               int steps){
    const int L = 512;
    int b = blockIdx.x;
    int k = threadIdx.x;              // chunk id 0..63
    int s0 = k * 8;

    __shared__ float4 lds4[576];      // 9216 B = half chain

    const float* pphi = phi   + (size_t)b * L;
    const float* ppsi = psi   + (size_t)b * L;
    const float* pome = omega + (size_t)b * L;

    float4 ps0 = ((const float4*)(ppsi + s0))[0];
    float4 ps1 = ((const float4*)(ppsi + s0))[1];
    float4 om0 = ((const float4*)(pome + s0))[0];
    float4 om1 = ((const float4*)(pome + s0))[1];
    float4 ph0 = ((const float4*)(pphi + s0))[0];
    float4 ph1 = ((const float4*)(pphi + s0))[1];
    float phi8 = __shfl_down(ph0.x, 1);   // phi[s0+8] from lane k+1 (unused at k=63)

    float tpsi[8] = {ps0.x, ps0.y, ps0.z, ps0.w, ps1.x, ps1.y, ps1.z, ps1.w};
    float tome[8] = {om0.x, om0.y, om0.z, om0.w, om1.x, om1.y, om1.z, om1.w};
    float tphi[8] = {ph0.y, ph0.z, ph0.w, ph1.x, ph1.y, ph1.z, ph1.w, phi8};

    // Pass 1: local chunk atoms in registers (R9/R15-proven).
    V3 A, Bv, C;
    if (k == 0){
        A = {NIX, NIY, NIZ}; Bv = {CAX, CAY, CAZ}; C = {CIX, CIY, CIZ};
    } else {
        A = {A0X, A0Y, 0.f}; Bv = {-1.54f, 0.f, 0.f}; C = {0.f, 0.f, 0.f};
    }
    V3 locA[8], locB[8], locC[8];
    #pragma unroll
    for (int s = 0; s < 8; ++s){
        if (s0 + s < steps)
            step3(A, Bv, C, tpsi[s], tome[s], tphi[s]);
        locA[s] = A; locB[s] = Bv; locC[s] = C;   // k63 s7: dup, never staged
    }
    Xform V = frame_of(A, Bv, C);

    // Pass 2: in-wave inclusive scan (proven R2..R17).
    #pragma unroll
    for (int d = 1; d < 64; d <<= 1){
        Xform Pr = shfl_up_xf(V, d);
        if (k >= d) V = xcompose(Pr, V);
    }
    Xform Wp = shfl_up_xf(V, 1);      // W_{k-1} at lane k (lane 0 unused)

    // Pass 3: transform local atoms to world IN PLACE (R9/R15-proven).
    if (k != 0){
        #pragma unroll
        for (int s = 0; s < 8; ++s){
            locA[s] = xapply(Wp, locA[s]);
            locB[s] = xapply(Wp, locB[s]);
            locC[s] = xapply(Wp, locC[s]);
        }
    }

    // Neighbor row (shifted window): lane k's output rows are 8k..8k+7 =
    // lane k-1's last row (global row 8k) + own steps s=0..6 (rows 8k+1..8k+7).
    V3 nA, nB, nC;
    nA.x = __shfl_up(locA[7].x, 1); nA.y = __shfl_up(locA[7].y, 1); nA.z = __shfl_up(locA[7].z, 1);
    nB.x = __shfl_up(locB[7].x, 1); nB.y = __shfl_up(locB[7].y, 1); nB.z = __shfl_up(locB[7].z, 1);
    nC.x = __shfl_up(locC[7].x, 1); nC.y = __shfl_up(locC[7].y, 1); nC.z = __shfl_up(locC[7].z, 1);
    if (k == 0){                       // row 0 = init triple
        nA = {NIX, NIY, NIZ}; nB = {CAX, CAY, CAZ}; nC = {CIX, CIY, CIZ};
    }

    int m = k & 31;                    // lane offset within half
    int p0 = 18 * m;                   // float4 base within half buffer
    float4* o4 = (float4*)(out + (size_t)b * 4608u);

    // Half 0: lanes 0..31 stage rows 0..255, whole wave flushes.
    if (k < 32){
        stage36(lds4, p0,     nA, nB, nC, locA[0], locB[0], locC[0],
                              locA[1], locB[1], locC[1], locA[2], locB[2], locC[2]);
        stage36(lds4, p0 + 9, locA[3], locB[3], locC[3], locA[4], locB[4], locC[4],
                              locA[5], locB[5], locC[5], locA[6], locB[6], locC[6]);
    }
    __syncthreads();
    #pragma unroll
    for (int i = 0; i < 9; ++i){
        int q = i * 64 + k;
        o4[q] = lds4[q ^ ((q >> 6) & 7)];
    }
    __syncthreads();

    // Half 1: lanes 32..63 stage rows 256..511, whole wave flushes.
    if (k >= 32){
        stage36(lds4, p0,     nA, nB, nC, locA[0], locB[0], locC[0],
                              locA[1], locB[1], locC[1], locA[2], locB[2], locC[2]);
        stage36(lds4, p0 + 9, locA[3], locB[3], locC[3], locA[4], locB[4], locC[4],
                              locA[5], locB[5], locC[5], locA[6], locB[6], locC[6]);
    }
    __syncthreads();
    #pragma unroll
    for (int i = 0; i < 9; ++i){
        int q = i * 64 + k;
        o4[576 + q] = lds4[q ^ ((q >> 6) & 7)];
    }
}

// ---- Fallback: sequential one-thread-per-chain (general sizes) ----
__global__ void nerf_seq_kernel(const float* __restrict__ phi,
                                const float* __restrict__ psi,
                                const float* __restrict__ omega,
                                float* __restrict__ out,
                                int B, int L, int steps){
    int b = blockIdx.x * blockDim.x + threadIdx.x;
    if (b >= B) return;
    V3 A  = {NIX, NIY, NIZ};
    V3 Bv = {CAX, CAY, CAZ};
    V3 C  = {CIX, CIY, CIZ};
    float* o = out + (size_t)b * 9u * (size_t)(steps + 1);
    o[0]=A.x;  o[1]=A.y;  o[2]=A.z;
    o[3]=Bv.x; o[4]=Bv.y; o[5]=Bv.z;
    o[6]=C.x;  o[7]=C.y;  o[8]=C.z;
    const float* pphi = phi   + (size_t)b * L;
    const float* ppsi = psi   + (size_t)b * L;
    const float* pome = omega + (size_t)b * L;
    for (int s = 0; s < steps; ++s){
        step3(A, Bv, C, ppsi[s], pome[s], pphi[s + 1]);
        float* os = o + 9u * (size_t)(s + 1);
        os[0]=A.x;  os[1]=A.y;  os[2]=A.z;
        os[3]=Bv.x; os[4]=Bv.y; os[5]=Bv.z;
        os[6]=C.x;  os[7]=C.y;  os[8]=C.z;
    }
}

extern "C" void kernel_launch(void* const* d_in, const int* in_sizes, int n_in,
                              void* d_out, int out_size, void* d_ws, size_t ws_size,
                              hipStream_t stream) {
    const float* phi   = (const float*)d_in[0];
    const float* psi   = (const float*)d_in[1];
    const float* omega = (const float*)d_in[2];
    float* out = (float*)d_out;

    const int L = 512;
    int B = in_sizes[0] / L;
    int steps = out_size / (9 * B) - 1;

    if (steps == 511 && in_sizes[0] == B * 512) {
        nerf_half<<<B, 64, 0, stream>>>(phi, psi, omega, out, steps);
    } else {
        int block = 64;
        int grid = (B + block - 1) / block;
        nerf_seq_kernel<<<grid, block, 0, stream>>>(phi, psi, omega, out, B, L, steps);
    }
}